// Round 1
// baseline (786.176 us; speedup 1.0000x reference)
//
#include <hip/hip_runtime.h>
#include <stdint.h>

typedef _Float16 f16;
typedef __attribute__((ext_vector_type(8))) _Float16 f16x8;
typedef __attribute__((ext_vector_type(4))) float f32x4;

#define MFMA(a, b, c) __builtin_amdgcn_mfma_f32_16x16x32_f16((a), (b), (c), 0, 0, 0)

static constexpr int C = 192;     // channels
static constexpr int N = 256;     // tokens per window
// windows: 1024 = B(4) * 16 * 16 ; token n = i*16 + j (i: H-offset, j: W-offset)

// ---------------- kernel 0: convert weights fp32 -> f16 ----------------
__global__ void wconv_kernel(const float* __restrict__ qkv_w, const float* __restrict__ proj_w,
                             f16* __restrict__ wq, f16* __restrict__ wp) {
    int i = blockIdx.x * 256 + threadIdx.x;
    if (i < 576 * 192) wq[i] = (f16)qkv_w[i];
    if (i < 192 * 192) wp[i] = (f16)proj_w[i];
}

// ---------------- kernel 1: QKV projection over a 64-token tile ----------------
// grid: 4096 = 1024 windows * 4 token-blocks ; block: 256 threads (4 waves)
// Writes qT/kT as [win][token][c] (token-major) and v as [win][c][token].
#define XS 200  // LDS row stride (f16) for x tile: 16B-aligned rows
__global__ __launch_bounds__(256, 4)
void qkv_kernel(const float* __restrict__ x, const f16* __restrict__ wq,
                const float* __restrict__ qkv_b,
                f16* __restrict__ qT, f16* __restrict__ kT, f16* __restrict__ vv) {
    __shared__ f16 xs[64 * XS];  // [token_local][c]
    const int tid = threadIdx.x;
    const int wg = blockIdx.x;
    const int win = wg >> 2, tb = wg & 3;
    const int batch = win >> 8, wh = (win >> 4) & 15, ww = win & 15;
    const int i0 = tb * 4;  // first window-row of this 64-token block

    // stage x tile -> xs[token][c] (f16), coalesced float4 reads
    for (int e = 0; e < 12; ++e) {
        int f = e * 1024 + tid * 4;      // covers c*64 + nl, 12288 elements
        int c = f >> 6, nl = f & 63;
        int i = nl >> 4, j = nl & 15;    // j in {0,4,8,12}
        const float4 v4 = *(const float4*)(x + (((size_t)(batch * C + c) * 256 + (wh * 16 + i0 + i)) * 256 + ww * 16 + j));
        xs[(nl + 0) * XS + c] = (f16)v4.x;
        xs[(nl + 1) * XS + c] = (f16)v4.y;
        xs[(nl + 2) * XS + c] = (f16)v4.z;
        xs[(nl + 3) * XS + c] = (f16)v4.w;
    }
    __syncthreads();

    const int wave = tid >> 6, lane = tid & 63, l15 = lane & 15, qd = lane >> 4;
    // 9 row-blocks of 64 output rows (576 = 3*Q + 3*K + 3*V blocks)
    for (int rb = wave; rb < 9; rb += 4) {
        f32x4 acc[4][4] = {};  // [mi][ti]
#pragma unroll
        for (int k = 0; k < 6; ++k) {
            const int c0 = k * 32 + qd * 8;
            f16x8 af[4], bf[4];
#pragma unroll
            for (int mi = 0; mi < 4; ++mi)
                af[mi] = *(const f16x8*)(wq + (rb * 64 + mi * 16 + l15) * C + c0);
#pragma unroll
            for (int ti = 0; ti < 4; ++ti)
                bf[ti] = *(const f16x8*)(xs + (ti * 16 + l15) * XS + c0);
#pragma unroll
            for (int mi = 0; mi < 4; ++mi)
#pragma unroll
                for (int ti = 0; ti < 4; ++ti)
                    acc[mi][ti] = MFMA(af[mi], bf[ti], acc[mi][ti]);
        }
        // epilogue: D[row=o][col=token], row = rb*64+mi*16+qd*4+r, col = ti*16+l15
#pragma unroll
        for (int mi = 0; mi < 4; ++mi) {
            const int ob = rb * 64 + mi * 16 + qd * 4;
            const float b0 = qkv_b[ob + 0], b1 = qkv_b[ob + 1], b2 = qkv_b[ob + 2], b3 = qkv_b[ob + 3];
#pragma unroll
            for (int ti = 0; ti < 4; ++ti) {
                const int tok = tb * 64 + ti * 16 + l15;
                const size_t gt = (size_t)win * 256 + tok;
                if (ob < 384) {  // Q or K: token-major, pack 4 consecutive c as one 8B store
                    union { f16 h[4]; uint2 u; } pk;
                    pk.h[0] = (f16)(acc[mi][ti][0] + b0);
                    pk.h[1] = (f16)(acc[mi][ti][1] + b1);
                    pk.h[2] = (f16)(acc[mi][ti][2] + b2);
                    pk.h[3] = (f16)(acc[mi][ti][3] + b3);
                    f16* dst = (ob < 192) ? (qT + gt * C + ob) : (kT + gt * C + (ob - 192));
                    *(uint2*)dst = pk.u;
                } else {        // V: channel-major
                    const int c2 = ob - 384;
                    vv[((size_t)win * C + c2 + 0) * 256 + tok] = (f16)(acc[mi][ti][0] + b0);
                    vv[((size_t)win * C + c2 + 1) * 256 + tok] = (f16)(acc[mi][ti][1] + b1);
                    vv[((size_t)win * C + c2 + 2) * 256 + tok] = (f16)(acc[mi][ti][2] + b2);
                    vv[((size_t)win * C + c2 + 3) * 256 + tok] = (f16)(acc[mi][ti][3] + b3);
                }
            }
        }
    }
}

// ---------------- kernel 2: fused attention + proj + residual ----------------
// grid: 4096 = 1024 windows * 4 query-row-blocks ; block: 256 threads (4 waves)
#define SQS 200  // sQ / sOT row stride (f16)
#define SPS 264  // sP row stride (f16)
__global__ __launch_bounds__(256, 4)
void attn_kernel(const f16* __restrict__ qT, const f16* __restrict__ kT,
                 const f16* __restrict__ vv, const f16* __restrict__ wp,
                 const float* __restrict__ proj_b, const float* __restrict__ x,
                 float* __restrict__ out) {
    __shared__ f16 sQ[64 * SQS];   // Q rows [n][c]; later reused as sOT [n][c]
    __shared__ f16 sP[64 * SPS];   // softmaxed scores [n][m]
    __shared__ float sRed[4][64];
    __shared__ float sMax[64];
    __shared__ float sSum[64];

    const int tid = threadIdx.x;
    const int wg = blockIdx.x;
    const int win = wg >> 2, rblk = wg & 3;
    const int n0 = rblk * 64;
    const int batch = win >> 8, wh = (win >> 4) & 15, ww = win & 15;
    const int wave = tid >> 6, lane = tid & 63, l15 = lane & 15, qd = lane >> 4;

    // stage 64 Q rows -> sQ (16B chunks)
    for (int it = 0; it < 6; ++it) {
        int ch = it * 256 + tid;              // 1536 chunks of 8 f16
        int n = ch / 24, c8 = (ch % 24) * 8;
        *(f16x8*)(sQ + n * SQS + c8) = *(const f16x8*)(qT + ((size_t)win * 256 + n0 + n) * C + c8);
    }
    __syncthreads();

    // ---- phase S: scores S[n][m] = sum_c Q[c,n] K[c,m]; wave -> 64-col block
    f32x4 accS[4][4] = {};  // [mi: row subtile][ti: col subtile]
#pragma unroll
    for (int k = 0; k < 6; ++k) {
        const int c0 = k * 32 + qd * 8;
        f16x8 af[4], bf[4];
#pragma unroll
        for (int mi = 0; mi < 4; ++mi)
            af[mi] = *(const f16x8*)(sQ + (mi * 16 + l15) * SQS + c0);
#pragma unroll
        for (int ti = 0; ti < 4; ++ti)
            bf[ti] = *(const f16x8*)(kT + ((size_t)win * 256 + wave * 64 + ti * 16 + l15) * C + c0);
#pragma unroll
        for (int mi = 0; mi < 4; ++mi)
#pragma unroll
            for (int ti = 0; ti < 4; ++ti)
                accS[mi][ti] = MFMA(af[mi], bf[ti], accS[mi][ti]);
    }

    // row max (rows live in lanes of quad qd; 4 ti values per lane per row)
    float pm[4][4];
#pragma unroll
    for (int mi = 0; mi < 4; ++mi)
#pragma unroll
        for (int r = 0; r < 4; ++r) {
            float m = accS[mi][0][r];
            m = fmaxf(m, accS[mi][1][r]);
            m = fmaxf(m, accS[mi][2][r]);
            m = fmaxf(m, accS[mi][3][r]);
#pragma unroll
            for (int d = 1; d < 16; d <<= 1) m = fmaxf(m, __shfl_xor(m, d, 64));
            pm[mi][r] = m;
        }
    if (l15 == 0) {
#pragma unroll
        for (int mi = 0; mi < 4; ++mi)
#pragma unroll
            for (int r = 0; r < 4; ++r) sRed[wave][mi * 16 + qd * 4 + r] = pm[mi][r];
    }
    __syncthreads();
    if (tid < 64)
        sMax[tid] = fmaxf(fmaxf(sRed[0][tid], sRed[1][tid]), fmaxf(sRed[2][tid], sRed[3][tid]));
    __syncthreads();

    // exp + row sum
    float ps[4][4];
#pragma unroll
    for (int mi = 0; mi < 4; ++mi)
#pragma unroll
        for (int r = 0; r < 4; ++r) {
            const float M = sMax[mi * 16 + qd * 4 + r];
            float s = 0.f;
#pragma unroll
            for (int ti = 0; ti < 4; ++ti) {
                float e = __expf(accS[mi][ti][r] - M);
                accS[mi][ti][r] = e;
                s += e;
            }
#pragma unroll
            for (int d = 1; d < 16; d <<= 1) s += __shfl_xor(s, d, 64);
            ps[mi][r] = s;
        }
    if (l15 == 0) {
#pragma unroll
        for (int mi = 0; mi < 4; ++mi)
#pragma unroll
            for (int r = 0; r < 4; ++r) sRed[wave][mi * 16 + qd * 4 + r] = ps[mi][r];
    }
    __syncthreads();
    if (tid < 64) sSum[tid] = sRed[0][tid] + sRed[1][tid] + sRed[2][tid] + sRed[3][tid];
    // write P (f16) to LDS: sP[n][m]
#pragma unroll
    for (int mi = 0; mi < 4; ++mi)
#pragma unroll
        for (int ti = 0; ti < 4; ++ti)
#pragma unroll
            for (int r = 0; r < 4; ++r)
                sP[(mi * 16 + qd * 4 + r) * SPS + wave * 64 + ti * 16 + l15] = (f16)accS[mi][ti][r];
    __syncthreads();

    // ---- phase O: O^T[n][c] = sum_m P[n][m] V[c][m]; wave -> 48-col (c) block
    f32x4 accO[4][3] = {};  // [tn][tc]
#pragma unroll
    for (int k = 0; k < 8; ++k) {
        const int m0 = k * 32 + qd * 8;
        f16x8 af[4], bf[3];
#pragma unroll
        for (int tn = 0; tn < 4; ++tn)
            af[tn] = *(const f16x8*)(sP + (tn * 16 + l15) * SPS + m0);
#pragma unroll
        for (int tc = 0; tc < 3; ++tc)
            bf[tc] = *(const f16x8*)(vv + ((size_t)win * C + wave * 48 + tc * 16 + l15) * 256 + m0);
#pragma unroll
        for (int tn = 0; tn < 4; ++tn)
#pragma unroll
            for (int tc = 0; tc < 3; ++tc)
                accO[tn][tc] = MFMA(af[tn], bf[tc], accO[tn][tc]);
    }
    // write scaled O^T to sOT (aliases sQ; all sQ reads completed before the sP barrier)
    f16* sOT = sQ;
#pragma unroll
    for (int tn = 0; tn < 4; ++tn)
#pragma unroll
        for (int r = 0; r < 4; ++r) {
            const int n = tn * 16 + qd * 4 + r;
            const float rs = 1.0f / sSum[n];
#pragma unroll
            for (int tc = 0; tc < 3; ++tc)
                sOT[n * SQS + wave * 48 + tc * 16 + l15] = (f16)(accO[tn][tc][r] * rs);
        }
    __syncthreads();

    // ---- phase proj: out[o][n] = sum_c Wp[o][c] O[c][n] + pb[o] + x ; wave -> 48 o-rows
    f32x4 accP[3][4] = {};  // [to][tn]
#pragma unroll
    for (int k = 0; k < 6; ++k) {
        const int c0 = k * 32 + qd * 8;
        f16x8 af[3], bf[4];
#pragma unroll
        for (int to = 0; to < 3; ++to)
            af[to] = *(const f16x8*)(wp + (wave * 48 + to * 16 + l15) * C + c0);
#pragma unroll
        for (int tn = 0; tn < 4; ++tn)
            bf[tn] = *(const f16x8*)(sOT + (tn * 16 + l15) * SQS + c0);
#pragma unroll
        for (int to = 0; to < 3; ++to)
#pragma unroll
            for (int tn = 0; tn < 4; ++tn)
                accP[to][tn] = MFMA(af[to], bf[tn], accP[to][tn]);
    }
    // epilogue: D[row=o][col=n]; h = wh*16 + rblk*4 + tn, w = ww*16 + l15
#pragma unroll
    for (int to = 0; to < 3; ++to)
#pragma unroll
        for (int r = 0; r < 4; ++r) {
            const int o = wave * 48 + to * 16 + qd * 4 + r;
            const float pb = proj_b[o];
#pragma unroll
            for (int tn = 0; tn < 4; ++tn) {
                const size_t idx = (((size_t)(batch * C + o) * 256) + wh * 16 + rblk * 4 + tn) * 256 + ww * 16 + l15;
                out[idx] = accP[to][tn][r] + pb + x[idx];
            }
        }
}

// ---------------- launch ----------------
extern "C" void kernel_launch(void* const* d_in, const int* in_sizes, int n_in,
                              void* d_out, int out_size, void* d_ws, size_t ws_size,
                              hipStream_t stream) {
    const float* x      = (const float*)d_in[0];
    const float* qkv_w  = (const float*)d_in[1];
    const float* qkv_b  = (const float*)d_in[2];
    const float* proj_w = (const float*)d_in[3];
    const float* proj_b = (const float*)d_in[4];
    float* out = (float*)d_out;

    char* ws = (char*)d_ws;
    const size_t QKV_BYTES = (size_t)1024 * 256 * 192 * 2;  // 100663296
    f16* qT = (f16*)(ws);
    f16* kT = (f16*)(ws + QKV_BYTES);
    f16* vv = (f16*)(ws + 2 * QKV_BYTES);
    f16* wq = (f16*)(ws + 3 * QKV_BYTES);
    f16* wp = (f16*)(ws + 3 * QKV_BYTES + 576 * 192 * 2);
    // total ws use: ~302.3 MB

    wconv_kernel<<<432, 256, 0, stream>>>(qkv_w, proj_w, wq, wp);
    qkv_kernel<<<4096, 256, 0, stream>>>(x, wq, qkv_b, qT, kT, vv);
    attn_kernel<<<4096, 256, 0, stream>>>(qT, kT, vv, wp, proj_b, x, out);
}

// Round 2
// 698.880 us; speedup vs baseline: 1.1249x; 1.1249x over previous
//
#include <hip/hip_runtime.h>
#include <stdint.h>

typedef _Float16 f16;
typedef __attribute__((ext_vector_type(8))) _Float16 f16x8;
typedef __attribute__((ext_vector_type(4))) float f32x4;

#define MFMA(a, b, c) __builtin_amdgcn_mfma_f32_16x16x32_f16((a), (b), (c), 0, 0, 0)

static constexpr int C = 192;     // channels
// windows: 1024 = B(4) * 16 * 16 ; token n = i*16 + j (i: H-offset, j: W-offset)
// Q/K packed layout: [win][c4 (c/4)][tok (256)][4]  (f16) -> coalesced D-layout stores
// V layout: [win][c][tok] (f16)

union U8x { uint2 u2[2]; f16x8 v; };

// ---------------- kernel 0: convert weights fp32 -> f16 ----------------
__global__ void wconv_kernel(const float* __restrict__ qkv_w, const float* __restrict__ proj_w,
                             f16* __restrict__ wq, f16* __restrict__ wp) {
    int i = blockIdx.x * 256 + threadIdx.x;
    if (i < 576 * 192) wq[i] = (f16)qkv_w[i];
    if (i < 192 * 192) wp[i] = (f16)proj_w[i];
}

// ---------------- kernel 1: QKV projection over a 64-token tile ----------------
// grid: 4096 = 1024 windows * 4 token-blocks ; block: 256 threads (4 waves)
#define XS 200  // LDS row stride (f16) for x tile: 16B-aligned rows
__global__ __launch_bounds__(256, 4)
void qkv_kernel(const float* __restrict__ x, const f16* __restrict__ wq,
                const float* __restrict__ qkv_b,
                f16* __restrict__ Qp, f16* __restrict__ Kp, f16* __restrict__ vv) {
    __shared__ f16 xs[64 * XS];  // [token_local][c]
    const int tid = threadIdx.x;
    const int wg = blockIdx.x;
    const int win = wg >> 2, tb = wg & 3;
    const int batch = win >> 8, wh = (win >> 4) & 15, ww = win & 15;
    const int i0 = tb * 4;  // first window-row of this 64-token block

    // stage x tile -> xs[token][c] (f16), coalesced float4 reads
    for (int e = 0; e < 12; ++e) {
        int f = e * 1024 + tid * 4;      // covers c*64 + nl, 12288 elements
        int c = f >> 6, nl = f & 63;
        int i = nl >> 4, j = nl & 15;    // j in {0,4,8,12}
        const float4 v4 = *(const float4*)(x + (((size_t)(batch * C + c) * 256 + (wh * 16 + i0 + i)) * 256 + ww * 16 + j));
        xs[(nl + 0) * XS + c] = (f16)v4.x;
        xs[(nl + 1) * XS + c] = (f16)v4.y;
        xs[(nl + 2) * XS + c] = (f16)v4.z;
        xs[(nl + 3) * XS + c] = (f16)v4.w;
    }
    __syncthreads();

    const int wave = tid >> 6, lane = tid & 63, l15 = lane & 15, qd = lane >> 4;
    // 9 row-blocks of 64 output rows (576 = 3*Q + 3*K + 3*V blocks)
    for (int rb = wave; rb < 9; rb += 4) {
        f32x4 acc[4][4] = {};  // [mi][ti]
#pragma unroll
        for (int k = 0; k < 6; ++k) {
            const int c0 = k * 32 + qd * 8;
            f16x8 af[4], bf[4];
#pragma unroll
            for (int mi = 0; mi < 4; ++mi)
                af[mi] = *(const f16x8*)(wq + (rb * 64 + mi * 16 + l15) * C + c0);
#pragma unroll
            for (int ti = 0; ti < 4; ++ti)
                bf[ti] = *(const f16x8*)(xs + (ti * 16 + l15) * XS + c0);
#pragma unroll
            for (int mi = 0; mi < 4; ++mi)
#pragma unroll
                for (int ti = 0; ti < 4; ++ti)
                    acc[mi][ti] = MFMA(af[mi], bf[ti], acc[mi][ti]);
        }
        // epilogue: D[row=o][col=token], row = rb*64+mi*16+qd*4+r, col = ti*16+l15
#pragma unroll
        for (int mi = 0; mi < 4; ++mi) {
            const int ob = rb * 64 + mi * 16 + qd * 4;
            const float b0 = qkv_b[ob + 0], b1 = qkv_b[ob + 1], b2 = qkv_b[ob + 2], b3 = qkv_b[ob + 3];
#pragma unroll
            for (int ti = 0; ti < 4; ++ti) {
                const int tok = tb * 64 + ti * 16 + l15;
                if (ob < 384) {  // Q or K: packed-c4 layout, coalesced 8B stores
                    union { f16 h[4]; uint2 u; } pk;
                    pk.h[0] = (f16)(acc[mi][ti][0] + b0);
                    pk.h[1] = (f16)(acc[mi][ti][1] + b1);
                    pk.h[2] = (f16)(acc[mi][ti][2] + b2);
                    pk.h[3] = (f16)(acc[mi][ti][3] + b3);
                    const int c4 = (ob < 192) ? (ob >> 2) : ((ob - 192) >> 2);
                    f16* base = (ob < 192) ? Qp : Kp;
                    *(uint2*)(base + (((size_t)win * 48 + c4) * 256 + tok) * 4) = pk.u;
                } else {        // V: channel-major
                    const int c2 = ob - 384;
                    vv[((size_t)win * C + c2 + 0) * 256 + tok] = (f16)(acc[mi][ti][0] + b0);
                    vv[((size_t)win * C + c2 + 1) * 256 + tok] = (f16)(acc[mi][ti][1] + b1);
                    vv[((size_t)win * C + c2 + 2) * 256 + tok] = (f16)(acc[mi][ti][2] + b2);
                    vv[((size_t)win * C + c2 + 3) * 256 + tok] = (f16)(acc[mi][ti][3] + b3);
                }
            }
        }
    }
}

// ---------------- kernel 2: fused attention + proj + residual ----------------
// grid: 4096 ; block: 256 threads (4 waves). XCD swizzle: 4 WGs of one window -> same XCD.
#define SQS 200  // sQ / sOT row stride (f16)
#define SPS 136  // sP row stride (f16), holds one 128-col chunk
__global__ __launch_bounds__(256, 3)
void attn_kernel(const f16* __restrict__ Qp, const f16* __restrict__ Kp,
                 const f16* __restrict__ vv, const f16* __restrict__ wp,
                 const float* __restrict__ proj_b, const float* __restrict__ x,
                 float* __restrict__ out) {
    __shared__ f16 sQ[64 * SQS];   // Q rows [n][c]; later reused as sOT [n][c]
    __shared__ f16 sP[64 * SPS];   // softmaxed scores, one 128-col chunk
    __shared__ float sRed[4][64];
    __shared__ float sMax[64];
    __shared__ float sSum[64];

    const int tid = threadIdx.x;
    const int wg = blockIdx.x;
    // swizzle: win = ((wg>>5)<<3) | (wg&7), rblk = (wg>>3)&3  (window's 4 WGs share XCD wg&7)
    const int win = ((wg >> 5) << 3) | (wg & 7);
    const int rblk = (wg >> 3) & 3;
    const int n0 = rblk * 64;
    const int batch = win >> 8, wh = (win >> 4) & 15, ww = win & 15;
    const int wave = tid >> 6, lane = tid & 63, l15 = lane & 15, qd = lane >> 4;

    // stage 64 Q rows -> sQ from packed layout (coalesced 8B reads)
    for (int it = 0; it < 12; ++it) {
        int ch = it * 256 + tid;              // 3072 = 64 n * 48 c4
        int n = ch & 63, c4 = ch >> 6;
        *(uint2*)(sQ + n * SQS + c4 * 4) =
            *(const uint2*)(Qp + (((size_t)win * 48 + c4) * 256 + n0 + n) * 4);
    }
    __syncthreads();

    // ---- phase S: scores S[n][m]; wave -> 64-col block
    f32x4 accS[4][4] = {};  // [mi: row subtile][ti: col subtile]
#pragma unroll
    for (int k = 0; k < 6; ++k) {
        const int c0 = k * 32 + qd * 8;
        const int c4 = c0 >> 2;
        f16x8 af[4], bf[4];
#pragma unroll
        for (int mi = 0; mi < 4; ++mi)
            af[mi] = *(const f16x8*)(sQ + (mi * 16 + l15) * SQS + c0);
#pragma unroll
        for (int ti = 0; ti < 4; ++ti) {
            const int m = wave * 64 + ti * 16 + l15;
            const size_t a = (((size_t)win * 48 + c4) * 256 + m) * 4;
            U8x b;
            b.u2[0] = *(const uint2*)(Kp + a);
            b.u2[1] = *(const uint2*)(Kp + a + 1024);  // c4+1 block
            bf[ti] = b.v;
        }
#pragma unroll
        for (int mi = 0; mi < 4; ++mi)
#pragma unroll
            for (int ti = 0; ti < 4; ++ti)
                accS[mi][ti] = MFMA(af[mi], bf[ti], accS[mi][ti]);
    }

    // row max
    float pm[4][4];
#pragma unroll
    for (int mi = 0; mi < 4; ++mi)
#pragma unroll
        for (int r = 0; r < 4; ++r) {
            float m = fmaxf(fmaxf(accS[mi][0][r], accS[mi][1][r]),
                            fmaxf(accS[mi][2][r], accS[mi][3][r]));
#pragma unroll
            for (int d = 1; d < 16; d <<= 1) m = fmaxf(m, __shfl_xor(m, d, 64));
            pm[mi][r] = m;
        }
    if (l15 == 0) {
#pragma unroll
        for (int mi = 0; mi < 4; ++mi)
#pragma unroll
            for (int r = 0; r < 4; ++r) sRed[wave][mi * 16 + qd * 4 + r] = pm[mi][r];
    }
    __syncthreads();
    if (tid < 64)
        sMax[tid] = fmaxf(fmaxf(sRed[0][tid], sRed[1][tid]), fmaxf(sRed[2][tid], sRed[3][tid]));
    __syncthreads();

    // exp + row sum; pack P to f16 early to cut VGPR pressure
    union PK { f16 h[4]; uint2 u; };
    PK pH[4][4];
    float ps[4][4];
#pragma unroll
    for (int mi = 0; mi < 4; ++mi)
#pragma unroll
        for (int r = 0; r < 4; ++r) {
            const float M = sMax[mi * 16 + qd * 4 + r];
            float s = 0.f;
#pragma unroll
            for (int ti = 0; ti < 4; ++ti) {
                float e = __expf(accS[mi][ti][r] - M);
                pH[mi][ti].h[r] = (f16)e;
                s += e;
            }
#pragma unroll
            for (int d = 1; d < 16; d <<= 1) s += __shfl_xor(s, d, 64);
            ps[mi][r] = s;
        }
    if (l15 == 0) {
#pragma unroll
        for (int mi = 0; mi < 4; ++mi)
#pragma unroll
            for (int r = 0; r < 4; ++r) sRed[wave][mi * 16 + qd * 4 + r] = ps[mi][r];
    }
    __syncthreads();
    if (tid < 64) sSum[tid] = sRed[0][tid] + sRed[1][tid] + sRed[2][tid] + sRed[3][tid];

    // ---- phase O over two 128-col chunks of P; wave -> 48-c block
    f32x4 accO[4][3] = {};  // [tn][tc]
#pragma unroll
    for (int h = 0; h < 2; ++h) {
        if ((wave >> 1) == h) {
            const int cl = (wave & 1) * 64;
#pragma unroll
            for (int mi = 0; mi < 4; ++mi)
#pragma unroll
                for (int ti = 0; ti < 4; ++ti)
#pragma unroll
                    for (int r = 0; r < 4; ++r)
                        sP[(mi * 16 + qd * 4 + r) * SPS + cl + ti * 16 + l15] = pH[mi][ti].h[r];
        }
        __syncthreads();
#pragma unroll
        for (int k = 0; k < 4; ++k) {
            const int ml = k * 32 + qd * 8;        // local col in chunk
            const int m0 = h * 128 + ml;           // global m
            f16x8 af[4], bf[3];
#pragma unroll
            for (int tn = 0; tn < 4; ++tn)
                af[tn] = *(const f16x8*)(sP + (tn * 16 + l15) * SPS + ml);
#pragma unroll
            for (int tc = 0; tc < 3; ++tc)
                bf[tc] = *(const f16x8*)(vv + ((size_t)win * C + wave * 48 + tc * 16 + l15) * 256 + m0);
#pragma unroll
            for (int tn = 0; tn < 4; ++tn)
#pragma unroll
                for (int tc = 0; tc < 3; ++tc)
                    accO[tn][tc] = MFMA(af[tn], bf[tc], accO[tn][tc]);
        }
        if (h == 0) __syncthreads();  // protect sP before chunk-1 overwrite
    }

    // write scaled O^T to sOT (aliases sQ; sQ reads all done in phase S)
    f16* sOT = sQ;
#pragma unroll
    for (int tn = 0; tn < 4; ++tn)
#pragma unroll
        for (int r = 0; r < 4; ++r) {
            const int n = tn * 16 + qd * 4 + r;
            const float rs = 1.0f / sSum[n];
#pragma unroll
            for (int tc = 0; tc < 3; ++tc)
                sOT[n * SQS + wave * 48 + tc * 16 + l15] = (f16)(accO[tn][tc][r] * rs);
        }
    __syncthreads();

    // ---- phase proj: out[o][n] = Wp[o][:]·O[:,n] + pb[o] + x ; wave -> 48 o-rows
    f32x4 accP[3][4] = {};  // [to][tn]
#pragma unroll
    for (int k = 0; k < 6; ++k) {
        const int c0 = k * 32 + qd * 8;
        f16x8 af[3], bf[4];
#pragma unroll
        for (int to = 0; to < 3; ++to)
            af[to] = *(const f16x8*)(wp + (wave * 48 + to * 16 + l15) * C + c0);
#pragma unroll
        for (int tn = 0; tn < 4; ++tn)
            bf[tn] = *(const f16x8*)(sOT + (tn * 16 + l15) * SQS + c0);
#pragma unroll
        for (int to = 0; to < 3; ++to)
#pragma unroll
            for (int tn = 0; tn < 4; ++tn)
                accP[to][tn] = MFMA(af[to], bf[tn], accP[to][tn]);
    }
    // epilogue: D[row=o][col=n]; h = wh*16 + rblk*4 + tn, w = ww*16 + l15
#pragma unroll
    for (int to = 0; to < 3; ++to)
#pragma unroll
        for (int r = 0; r < 4; ++r) {
            const int o = wave * 48 + to * 16 + qd * 4 + r;
            const float pb = proj_b[o];
#pragma unroll
            for (int tn = 0; tn < 4; ++tn) {
                const size_t idx = (((size_t)(batch * C + o) * 256) + wh * 16 + rblk * 4 + tn) * 256 + ww * 16 + l15;
                out[idx] = accP[to][tn][r] + pb + x[idx];
            }
        }
}

// ---------------- launch ----------------
extern "C" void kernel_launch(void* const* d_in, const int* in_sizes, int n_in,
                              void* d_out, int out_size, void* d_ws, size_t ws_size,
                              hipStream_t stream) {
    const float* x      = (const float*)d_in[0];
    const float* qkv_w  = (const float*)d_in[1];
    const float* qkv_b  = (const float*)d_in[2];
    const float* proj_w = (const float*)d_in[3];
    const float* proj_b = (const float*)d_in[4];
    float* out = (float*)d_out;

    char* ws = (char*)d_ws;
    const size_t QKV_BYTES = (size_t)1024 * 256 * 192 * 2;  // 100663296
    f16* Qp = (f16*)(ws);
    f16* Kp = (f16*)(ws + QKV_BYTES);
    f16* vv = (f16*)(ws + 2 * QKV_BYTES);
    f16* wq = (f16*)(ws + 3 * QKV_BYTES);
    f16* wp = (f16*)(ws + 3 * QKV_BYTES + 576 * 192 * 2);

    wconv_kernel<<<432, 256, 0, stream>>>(qkv_w, proj_w, wq, wp);
    qkv_kernel<<<4096, 256, 0, stream>>>(x, wq, qkv_b, Qp, Kp, vv);
    attn_kernel<<<4096, 256, 0, stream>>>(Qp, Kp, vv, wp, proj_b, x, out);
}